// Round 2
// baseline (409.124 us; speedup 1.0000x reference)
//
#include <hip/hip_runtime.h>
#include <stdint.h>

// FPQuantizer: elementwise fp8_e4m3-style "flex" quantization.
// Math (after noting clip(x,-rowmax,rowmax) is an identity):
//   bias = bf16(16 - log2(448) + log2(1.9375) - 1) = 7.15625 (exact in fp32)
//   e = max(floor(log2|x| + bias), 1)
//   scale = 2^(e - 5 - bias) = 2^(e-13) * 1.7947090864...   (2^(27/32))
//   out = rint(x/scale) * scale
//
// Exact-floor via bits: |x| = mant * 2^E, mant in [1,2):
//   floor(log2|x| + 7.15625) = E + 7 + (mant > T),  T = rnd_down_f32(2^(27/32))
//   T = 15055111 / 2^23 = 1.79470908641815f
// scale bits: mantissa of 2^(27/32) = 0x65B907, biased exp = (e-13)+127 = e+114.
// This equals correctly-rounded exp2f(e-12.15625) (exact 2^k scaling of the
// correctly-rounded constant 2^(-5/32)), matching numpy's libm exp2 bitwise.

typedef float f32x4 __attribute__((ext_vector_type(4)));

__device__ __forceinline__ float fpq_one(float xv) {
    unsigned b = __float_as_uint(xv) & 0x7FFFFFFFu;
    int expfield = (int)(b >> 23);
    float mant = __uint_as_float((b & 0x7FFFFFu) | 0x3F800000u);
    int e = expfield - 127 + 7 + (mant > 1.79470908641815f ? 1 : 0);
    if (expfield == 0) e = 1;      // zero / denormal -> clamp path
    if (e < 1) e = 1;              // log_scales = max(log_scales, 1)
    float scale = __int_as_float(((e + 114) << 23) | 0x65B907);
    float q = xv / scale;          // IEEE fp32 div, matches np
    float r = __builtin_rintf(q);  // round half-to-even, matches np.round
    return r * scale;
}

__global__ __launch_bounds__(256) void fpq_vec4(const float* __restrict__ in,
                                                float* __restrict__ out, int n4) {
    int idx = blockIdx.x * blockDim.x + threadIdx.x;
    if (idx >= n4) return;
    const f32x4* in4 = (const f32x4*)in;
    f32x4* out4 = (f32x4*)out;
    f32x4 v = __builtin_nontemporal_load(&in4[idx]);
    f32x4 res;
    res.x = fpq_one(v.x);
    res.y = fpq_one(v.y);
    res.z = fpq_one(v.z);
    res.w = fpq_one(v.w);
    __builtin_nontemporal_store(res, &out4[idx]);
}

__global__ __launch_bounds__(256) void fpq_tail(const float* __restrict__ in,
                                                float* __restrict__ out,
                                                int start, int n) {
    int idx = start + blockIdx.x * blockDim.x + threadIdx.x;
    if (idx >= n) return;
    out[idx] = fpq_one(in[idx]);
}

extern "C" void kernel_launch(void* const* d_in, const int* in_sizes, int n_in,
                              void* d_out, int out_size, void* d_ws, size_t ws_size,
                              hipStream_t stream) {
    const float* x = (const float*)d_in[0];
    float* out = (float*)d_out;
    int n = in_sizes[0];           // 8192*8192 = 67108864
    int n4 = n / 4;
    if (n4 > 0) {
        int block = 256;
        int grid = (n4 + block - 1) / block;
        fpq_vec4<<<grid, block, 0, stream>>>(x, out, n4);
    }
    int tail_start = n4 * 4;
    int tail = n - tail_start;
    if (tail > 0) {
        fpq_tail<<<1, 64, 0, stream>>>(x, out, tail_start, n);
    }
}